// Round 19
// baseline (273.763 us; speedup 1.0000x reference)
//
#include <hip/hip_runtime.h>

#define NN 50000
#define NE 800000
#define NG 512
#define INDIM 100
#define OUTD 24
#define LROW 72       // padded LDS row (ushorts): 144B stride, 16B-aligned
#define XROW 136      // padded LDS row for pre0 x-tile (ushorts)
#define NPART 8       // XCD count; partition = blockIdx & 7
#define PART_NODES 6250  // NN / NPART
#define CSR_CAP 64    // fixed csr stride per node; deg~Poisson(16), max~42
// k_prep block-role boundaries
#define B_WPREP 80
#define B_WPREP0 112   // +32
#define B_CNT0 308     // +196 (zero count[50000])
#define B_GP0 692      // +384 (zero gp[3*NG*64])

typedef __attribute__((ext_vector_type(8))) short short8;
typedef __attribute__((ext_vector_type(4))) float floatx4;

// bf16 raw-bits helpers (RNE pack)
__device__ inline float bf2f(unsigned short u) {
    unsigned v = (unsigned)u << 16;
    float f;
    __builtin_memcpy(&f, &v, 4);
    return f;
}
__device__ inline unsigned short f2bf(float f) {
    unsigned u;
    __builtin_memcpy(&u, &f, 4);
    u += 0x7fffu + ((u >> 16) & 1u);  // round-to-nearest-even
    return (unsigned short)(u >> 16);
}

// ---------------- prep: weight transposes + buffer zeroing, one dispatch ----------------

__global__ __launch_bounds__(256) void k_prep(const float* __restrict__ s0, const float* __restrict__ s1,
                                              const float* __restrict__ s2, const float* __restrict__ s3,
                                              const float* __restrict__ s4,
                                              const float* __restrict__ w1_0,
                                              unsigned short* __restrict__ wT,
                                              unsigned short* __restrict__ w0T,
                                              int* __restrict__ count,
                                              float* __restrict__ gp) {
    int b = blockIdx.x, tid = threadIdx.x;
    if (b < B_WPREP) {
        const float* srcs[5] = {s0, s1, s2, s3, s4};
        int id = b >> 4;
        int off = ((b & 15) << 8) + tid;
        int k = off >> 6, n = off & 63;
        wT[id * 4096 + n * 64 + k] = f2bf(srcs[id][k * 64 + n]);
    } else if (b < B_WPREP0) {
        int i = (b - B_WPREP) * 256 + tid;
        int n = i >> 7, k = i & 127;
        w0T[n * 128 + k] = (k < INDIM) ? f2bf(w1_0[k * 64 + n]) : 0;
    } else if (b < B_CNT0) {
        int i = (b - B_WPREP0) * 256 + tid;
        if (i < NN) count[i] = 0;
    } else {
        int i = (b - B_CNT0) * 256 + tid;
        if (i < 3 * NG * 64) gp[i] = 0.f;
    }
}

// ---------------- CSR fill: XCD-partitioned, fixed-stride ----------------
// ei is pure streaming (8x rescan) -> nontemporal loads keep it out of L2.

__global__ __launch_bounds__(256) void k_fill(const int* __restrict__ ei,
                                              int* __restrict__ count,
                                              int* __restrict__ csr) {
    int p = blockIdx.x & (NPART - 1);
    int slice = blockIdx.x >> 3;
    int nsl = gridDim.x >> 3;
    int lo = p * PART_NODES, hi = lo + PART_NODES;
    for (unsigned e = slice * 256u + threadIdx.x; e < NE; e += nsl * 256u) {
        int d = __builtin_nontemporal_load(&ei[NE + e]);
        int s = __builtin_nontemporal_load(&ei[e]);  // unconditional: coalesced
        if (d >= lo && d < hi) {
            int pos = atomicAdd(&count[d], 1);
            if (pos < CSR_CAP) csr[(size_t)d * CSR_CAP + pos] = s;
        }
    }
}

// ---------------- y0 = x @ w1_0 (no bias), MFMA, bf16 out ----------------

__global__ __launch_bounds__(256) void k_pre0(const float* __restrict__ x,
                                              const unsigned short* __restrict__ w1T,  // [64][128] bf16
                                              unsigned short* __restrict__ y) {
    __shared__ __align__(16) unsigned short xs[64 * XROW];
    int tid = threadIdx.x;
    int base = blockIdx.x * 64;
    for (int i = tid; i < 64 * 128; i += 256) {
        int r = i >> 7, c = i & 127;
        int node = base + r;
        float v = (c < INDIM && node < NN) ? __builtin_nontemporal_load(&x[(size_t)node * INDIM + c]) : 0.f;
        xs[r * XROW + c] = f2bf(v);
    }
    __syncthreads();
    int wave = tid >> 6, lane = tid & 63;
    int quad = lane >> 4, l15 = lane & 15;
#pragma unroll
    for (int nt = 0; nt < 4; ++nt) {
        floatx4 c = {0.f, 0.f, 0.f, 0.f};
#pragma unroll
        for (int kk = 0; kk < 4; ++kk) {
            short8 a = *(const short8*)&xs[(wave * 16 + l15) * XROW + kk * 32 + quad * 8];
            short8 bb = *(const short8*)&w1T[(nt * 16 + l15) * 128 + kk * 32 + quad * 8];
            c = __builtin_amdgcn_mfma_f32_16x16x32_bf16(a, bb, c, 0, 0, 0);
        }
        int col = nt * 16 + l15;
#pragma unroll
        for (int r = 0; r < 4; ++r) {
            int row = base + wave * 16 + quad * 4 + r;
            if (row < NN) y[(size_t)row * 64 + col] = f2bf(c[r]);
        }
    }
}

// ---------------- fused layer: 4-wave/16-node blocks, NT csr loads ----------------
// csr has zero reuse within a layer (12.8MB streamed) -> nontemporal loads stop
// it evicting y rows (the actual reuse target) from the 4MiB/XCD L2.

template <bool HAS_NEXT>
__global__ __launch_bounds__(256) void k_layer(const unsigned short* __restrict__ y,
                                               const int* __restrict__ count,
                                               const int* __restrict__ csr,
                                               const float* __restrict__ b1,
                                               const unsigned short* __restrict__ w2T,  // bf16 [n][k]
                                               const float* __restrict__ b2,
                                               const unsigned short* __restrict__ wnT,  // bf16 [n][k]
                                               unsigned short* __restrict__ ynext,
                                               const int* __restrict__ batch,
                                               float* __restrict__ gp) {
    __shared__ __align__(16) unsigned short tA[16 * LROW];
    __shared__ __align__(16) unsigned short tB[16 * LROW];
    int wave = threadIdx.x >> 6, lane = threadIdx.x & 63;
    int base = blockIdx.x * 16;  // NN = 3125 * 16 exactly
    float bias1 = b1[lane];

    // ---- gather: wave handles nodes wave*4..wave*4+3, 2 interleaved per pass ----
    for (int i = 0; i < 4; i += 2) {
        int nA = __builtin_amdgcn_readfirstlane(base + wave * 4 + i);
        int nB = __builtin_amdgcn_readfirstlane(base + wave * 4 + i + 1);
        int cA = min(count[nA], CSR_CAP);
        int cB = min(count[nB], CSR_CAP);
        const int* pA = csr + (size_t)nA * CSR_CAP;
        const int* pB = csr + (size_t)nB * CSR_CAP;
        float aA[4], aB[4];
        aA[0] = bf2f(y[(size_t)nA * 64 + lane]);
        aB[0] = bf2f(y[(size_t)nB * 64 + lane]);
        aA[1] = aA[2] = aA[3] = 0.f;
        aB[1] = aB[2] = aB[3] = 0.f;
        int eA = 0, eB = 0;
        while (eA + 8 <= cA && eB + 8 <= cB) {
            int iA[8], iB[8];
#pragma unroll
            for (int j = 0; j < 8; ++j) {
                iA[j] = __builtin_nontemporal_load(&pA[eA + j]);
                iB[j] = __builtin_nontemporal_load(&pB[eB + j]);
            }
            float vA[8], vB[8];
#pragma unroll
            for (int j = 0; j < 8; ++j) vA[j] = bf2f(y[(size_t)iA[j] * 64 + lane]);
#pragma unroll
            for (int j = 0; j < 8; ++j) vB[j] = bf2f(y[(size_t)iB[j] * 64 + lane]);
#pragma unroll
            for (int j = 0; j < 8; ++j) { aA[j & 3] += vA[j]; aB[j & 3] += vB[j]; }
            eA += 8; eB += 8;
        }
        for (; eA + 8 <= cA; eA += 8) {
            int idx[8];
#pragma unroll
            for (int j = 0; j < 8; ++j) idx[j] = __builtin_nontemporal_load(&pA[eA + j]);
#pragma unroll
            for (int j = 0; j < 8; ++j) aA[j & 3] += bf2f(y[(size_t)idx[j] * 64 + lane]);
        }
        if (eA + 4 <= cA) {
            int i0 = pA[eA], i1 = pA[eA + 1], i2 = pA[eA + 2], i3 = pA[eA + 3];
            aA[0] += bf2f(y[(size_t)i0 * 64 + lane]);
            aA[1] += bf2f(y[(size_t)i1 * 64 + lane]);
            aA[2] += bf2f(y[(size_t)i2 * 64 + lane]);
            aA[3] += bf2f(y[(size_t)i3 * 64 + lane]);
            eA += 4;
        }
        if (eA + 2 <= cA) {
            int i0 = pA[eA], i1 = pA[eA + 1];
            aA[0] += bf2f(y[(size_t)i0 * 64 + lane]);
            aA[1] += bf2f(y[(size_t)i1 * 64 + lane]);
            eA += 2;
        }
        if (eA < cA) aA[0] += bf2f(y[(size_t)pA[eA] * 64 + lane]);
        for (; eB + 8 <= cB; eB += 8) {
            int idx[8];
#pragma unroll
            for (int j = 0; j < 8; ++j) idx[j] = __builtin_nontemporal_load(&pB[eB + j]);
#pragma unroll
            for (int j = 0; j < 8; ++j) aB[j & 3] += bf2f(y[(size_t)idx[j] * 64 + lane]);
        }
        if (eB + 4 <= cB) {
            int i0 = pB[eB], i1 = pB[eB + 1], i2 = pB[eB + 2], i3 = pB[eB + 3];
            aB[0] += bf2f(y[(size_t)i0 * 64 + lane]);
            aB[1] += bf2f(y[(size_t)i1 * 64 + lane]);
            aB[2] += bf2f(y[(size_t)i2 * 64 + lane]);
            aB[3] += bf2f(y[(size_t)i3 * 64 + lane]);
            eB += 4;
        }
        if (eB + 2 <= cB) {
            int i0 = pB[eB], i1 = pB[eB + 1];
            aB[0] += bf2f(y[(size_t)i0 * 64 + lane]);
            aB[1] += bf2f(y[(size_t)i1 * 64 + lane]);
            eB += 2;
        }
        if (eB < cB) aB[0] += bf2f(y[(size_t)pB[eB] * 64 + lane]);

        float sA = (aA[0] + aA[1]) + (aA[2] + aA[3]);
        float sB = (aB[0] + aB[1]) + (aB[2] + aB[3]);
        tA[(wave * 4 + i) * LROW + lane]     = f2bf(fmaxf(sA + bias1, 0.f));
        tA[(wave * 4 + i + 1) * LROW + lane] = f2bf(fmaxf(sB + bias1, 0.f));
    }
    __syncthreads();

    int quad = lane >> 4, l15 = lane & 15;

    // ---- GEMM1: h = relu(t @ w2 + b2) -> tB; 4 n-tiles, 1 per wave ----
    short8 a_k0 = *(const short8*)&tA[l15 * LROW + quad * 8];
    short8 a_k1 = *(const short8*)&tA[l15 * LROW + 32 + quad * 8];
    {
        int col = wave * 16 + l15;
        short8 b_k0 = *(const short8*)&w2T[col * 64 + quad * 8];
        short8 b_k1 = *(const short8*)&w2T[col * 64 + 32 + quad * 8];
        floatx4 c = {0.f, 0.f, 0.f, 0.f};
        c = __builtin_amdgcn_mfma_f32_16x16x32_bf16(a_k0, b_k0, c, 0, 0, 0);
        c = __builtin_amdgcn_mfma_f32_16x16x32_bf16(a_k1, b_k1, c, 0, 0, 0);
        float bb = b2[col];
#pragma unroll
        for (int r = 0; r < 4; ++r) {
            float h = fmaxf(c[r] + bb, 0.f);  // inter-layer ReLU
            tB[(quad * 4 + r) * LROW + col] = f2bf(h);
        }
    }
    __syncthreads();

    // ---- block-level segmented pool: wave 0 scans 16 rows ----
    if (wave == 0) {
        float run = 0.f;
        int curg = batch[base];
        for (int r = 0; r < 16; ++r) {
            int g2 = batch[base + r];
            if (g2 != curg) {
                atomicAdd(&gp[curg * 64 + lane], run);
                run = 0.f;
                curg = g2;
            }
            run += bf2f(tB[r * LROW + lane]);
        }
        atomicAdd(&gp[curg * 64 + lane], run);
    }

    if (HAS_NEXT) {
        // ---- GEMM3: yn = h @ wnext; 1 n-tile per wave ----
        short8 h_k0 = *(const short8*)&tB[l15 * LROW + quad * 8];
        short8 h_k1 = *(const short8*)&tB[l15 * LROW + 32 + quad * 8];
        int col = wave * 16 + l15;
        short8 w_k0 = *(const short8*)&wnT[col * 64 + quad * 8];
        short8 w_k1 = *(const short8*)&wnT[col * 64 + 32 + quad * 8];
        floatx4 cy = {0.f, 0.f, 0.f, 0.f};
        cy = __builtin_amdgcn_mfma_f32_16x16x32_bf16(h_k0, w_k0, cy, 0, 0, 0);
        cy = __builtin_amdgcn_mfma_f32_16x16x32_bf16(h_k1, w_k1, cy, 0, 0, 0);
#pragma unroll
        for (int r = 0; r < 4; ++r) {
            int row = base + quad * 4 + r;
            ynext[(size_t)row * 64 + col] = f2bf(cy[r]);
        }
    }
}

// ---------------- final head: pooled-JK + ffn + out; graph size via binary search ----------------

__device__ inline int lbound(const int* __restrict__ b, int v) {
    int lo = 0, hi = NN;
    while (lo < hi) {
        int m = (lo + hi) >> 1;
        if (b[m] < v) lo = m + 1; else hi = m;
    }
    return lo;
}

__global__ __launch_bounds__(64) void k_final(const float* __restrict__ gp,   // [3][NG][64]
                                              const int* __restrict__ batch,  // sorted
                                              const float* __restrict__ jkw,  // fp32 [192][64]
                                              const float* __restrict__ jkb,
                                              const float* __restrict__ w1,
                                              const float* __restrict__ b1,
                                              const float* __restrict__ bng,
                                              const float* __restrict__ bnb,
                                              const float* __restrict__ bnm,
                                              const float* __restrict__ bnv,
                                              const float* __restrict__ w2,
                                              const float* __restrict__ b2,
                                              const float* __restrict__ ow,
                                              const float* __restrict__ ob,
                                              float* __restrict__ out) {
    __shared__ float gs[192];
    __shared__ float gv[64];
    __shared__ float t2[64];
    __shared__ float t3[64];
    int gr = blockIdx.x, lane = threadIdx.x;
    gs[lane]       = gp[0 * NG * 64 + gr * 64 + lane];
    gs[64 + lane]  = gp[1 * NG * 64 + gr * 64 + lane];
    gs[128 + lane] = gp[2 * NG * 64 + gr * 64 + lane];
    float cntf = (float)(lbound(batch, gr + 1) - lbound(batch, gr));
    __syncthreads();
    float acc = cntf * jkb[lane];
#pragma unroll 8
    for (int k = 0; k < 192; ++k) acc = fmaf(gs[k], jkw[k * 64 + lane], acc);
    gv[lane] = acc;
    __syncthreads();
    acc = b1[lane];
#pragma unroll 8
    for (int k = 0; k < 64; ++k) acc = fmaf(gv[k], w1[k * 64 + lane], acc);
    acc = (acc - bnm[lane]) * rsqrtf(bnv[lane] + 1e-5f) * bng[lane] + bnb[lane];
    t2[lane] = fmaxf(acc, 0.f);
    __syncthreads();
    float acc2 = b2[lane];
#pragma unroll 8
    for (int k = 0; k < 64; ++k) acc2 = fmaf(t2[k], w2[k * 64 + lane], acc2);
    t3[lane] = acc2;
    __syncthreads();
    if (lane < OUTD) {
        float acc3 = ob[lane];
#pragma unroll 8
        for (int k = 0; k < 64; ++k) acc3 = fmaf(t3[k], ow[k * OUTD + lane], acc3);
        out[gr * OUTD + lane] = acc3;
    }
}

extern "C" void kernel_launch(void* const* d_in, const int* in_sizes, int n_in,
                              void* d_out, int out_size, void* d_ws, size_t ws_size,
                              hipStream_t stream) {
    const float* x     = (const float*)d_in[0];
    const int*   ei    = (const int*)d_in[1];
    const int*   batch = (const int*)d_in[2];
    const float* w1_0 = (const float*)d_in[3];
    const float* b1_0 = (const float*)d_in[4];
    const float* w2_0 = (const float*)d_in[5];
    const float* b2_0 = (const float*)d_in[6];
    const float* w1_1 = (const float*)d_in[7];
    const float* b1_1 = (const float*)d_in[8];
    const float* w2_1 = (const float*)d_in[9];
    const float* b2_1 = (const float*)d_in[10];
    const float* w1_2 = (const float*)d_in[11];
    const float* b1_2 = (const float*)d_in[12];
    const float* w2_2 = (const float*)d_in[13];
    const float* b2_2 = (const float*)d_in[14];
    const float* jk_w = (const float*)d_in[15];
    const float* jk_b = (const float*)d_in[16];
    const float* ffn_w1 = (const float*)d_in[17];
    const float* ffn_b1 = (const float*)d_in[18];
    const float* bn_g = (const float*)d_in[19];
    const float* bn_b = (const float*)d_in[20];
    const float* bn_m = (const float*)d_in[21];
    const float* bn_v = (const float*)d_in[22];
    const float* ffn_w2 = (const float*)d_in[23];
    const float* ffn_b2 = (const float*)d_in[24];
    const float* out_w  = (const float*)d_in[25];
    const float* out_b  = (const float*)d_in[26];

    // workspace layout
    float* ws = (float*)d_ws;
    unsigned short* ya = (unsigned short*)ws;          // 3.2M bf16
    unsigned short* yb = ya + 3200000;                 // 3.2M bf16
    float* gp  = (float*)(yb + 3200000);               // 3 x NG x 64 fp32
    int*   count = (int*)(gp + 3 * NG * 64);           // 50000
    int*   csr   = count + NN;                         // NN * CSR_CAP ints = 12.8MB
    unsigned short* wT  = (unsigned short*)(csr + (size_t)NN * CSR_CAP);  // 5 x 4096 bf16
    unsigned short* w0T = wT + 5 * 4096;                                  // 64 x 128 bf16

    // ---- prep: weight transposes + zero count/gp (one dispatch) ----
    k_prep<<<B_GP0, 256, 0, stream>>>(w2_0, w2_1, w2_2, w1_1, w1_2, w1_0,
                                      wT, w0T, count, gp);

    // ---- CSR fill | y0 MFMA ----
    k_fill<<<NPART * 192, 256, 0, stream>>>(ei, count, csr);
    k_pre0<<<(NN + 63) / 64, 256, 0, stream>>>(x, w0T, ya);

    int nblk = NN / 16;  // 3125, exact
    // ---- layer 0 ----
    k_layer<true><<<nblk, 256, 0, stream>>>(ya, count, csr, b1_0,
                                            wT + 0 * 4096, b2_0, wT + 3 * 4096,
                                            yb, batch, gp + 0 * NG * 64);
    // ---- layer 1 ----
    k_layer<true><<<nblk, 256, 0, stream>>>(yb, count, csr, b1_1,
                                            wT + 1 * 4096, b2_1, wT + 4 * 4096,
                                            ya, batch, gp + 1 * NG * 64);
    // ---- layer 2 ----
    k_layer<false><<<nblk, 256, 0, stream>>>(ya, count, csr, b1_2,
                                             wT + 2 * 4096, b2_2, nullptr,
                                             nullptr, batch, gp + 2 * NG * 64);

    // ---- head (pooled-JK + ffn + out; graph sizes via binary search) ----
    k_final<<<NG, 64, 0, stream>>>(gp, batch, jk_w, jk_b,
                                   ffn_w1, ffn_b1, bn_g, bn_b, bn_m, bn_v,
                                   ffn_w2, ffn_b2, out_w, out_b, (float*)d_out);
}

// Round 20
// 262.579 us; speedup vs baseline: 1.0426x; 1.0426x over previous
//
#include <hip/hip_runtime.h>

#define NN 50000
#define NE 800000
#define NG 512
#define INDIM 100
#define OUTD 24
#define LROW 72       // padded LDS row (ushorts): 144B stride, 16B-aligned
#define XROW 136      // padded LDS row for pre0 x-tile (ushorts)
#define NPART 8       // XCD count; partition = blockIdx & 7
#define PART_NODES 6250  // NN / NPART
#define CSR_CAP 64    // fixed csr stride per node; deg~Poisson(16), max~42
// k_prep block-role boundaries
#define B_WPREP 80
#define B_WPREP0 112   // +32
#define B_CNT0 308     // +196 (zero count[50000])
#define B_GP0 692      // +384 (zero gp[3*NG*64])

typedef __attribute__((ext_vector_type(8))) short short8;
typedef __attribute__((ext_vector_type(4))) float floatx4;

// bf16 raw-bits helpers (RNE pack)
__device__ inline float bf2f(unsigned short u) {
    unsigned v = (unsigned)u << 16;
    float f;
    __builtin_memcpy(&f, &v, 4);
    return f;
}
__device__ inline unsigned short f2bf(float f) {
    unsigned u;
    __builtin_memcpy(&u, &f, 4);
    u += 0x7fffu + ((u >> 16) & 1u);  // round-to-nearest-even
    return (unsigned short)(u >> 16);
}

// ---------------- prep: weight transposes + buffer zeroing, one dispatch ----------------

__global__ __launch_bounds__(256) void k_prep(const float* __restrict__ s0, const float* __restrict__ s1,
                                              const float* __restrict__ s2, const float* __restrict__ s3,
                                              const float* __restrict__ s4,
                                              const float* __restrict__ w1_0,
                                              unsigned short* __restrict__ wT,
                                              unsigned short* __restrict__ w0T,
                                              int* __restrict__ count,
                                              float* __restrict__ gp) {
    int b = blockIdx.x, tid = threadIdx.x;
    if (b < B_WPREP) {
        const float* srcs[5] = {s0, s1, s2, s3, s4};
        int id = b >> 4;
        int off = ((b & 15) << 8) + tid;
        int k = off >> 6, n = off & 63;
        wT[id * 4096 + n * 64 + k] = f2bf(srcs[id][k * 64 + n]);
    } else if (b < B_WPREP0) {
        int i = (b - B_WPREP) * 256 + tid;
        int n = i >> 7, k = i & 127;
        w0T[n * 128 + k] = (k < INDIM) ? f2bf(w1_0[k * 64 + n]) : 0;
    } else if (b < B_CNT0) {
        int i = (b - B_WPREP0) * 256 + tid;
        if (i < NN) count[i] = 0;
    } else {
        int i = (b - B_CNT0) * 256 + tid;
        if (i < 3 * NG * 64) gp[i] = 0.f;
    }
}

// ---------------- CSR fill: XCD-partitioned, fixed-stride ----------------

__global__ __launch_bounds__(256) void k_fill(const int* __restrict__ ei,
                                              int* __restrict__ count,
                                              int* __restrict__ csr) {
    int p = blockIdx.x & (NPART - 1);
    int slice = blockIdx.x >> 3;
    int nsl = gridDim.x >> 3;
    int lo = p * PART_NODES, hi = lo + PART_NODES;
    for (unsigned e = slice * 256u + threadIdx.x; e < NE; e += nsl * 256u) {
        int d = ei[NE + e];
        int s = ei[e];  // unconditional: keeps the read coalesced
        if (d >= lo && d < hi) {
            int pos = atomicAdd(&count[d], 1);
            if (pos < CSR_CAP) csr[(size_t)d * CSR_CAP + pos] = s;
        }
    }
}

// ---------------- y0 = x @ w1_0 (no bias), MFMA, bf16 out ----------------

__global__ __launch_bounds__(256) void k_pre0(const float* __restrict__ x,
                                              const unsigned short* __restrict__ w1T,  // [64][128] bf16
                                              unsigned short* __restrict__ y) {
    __shared__ __align__(16) unsigned short xs[64 * XROW];
    int tid = threadIdx.x;
    int base = blockIdx.x * 64;
    for (int i = tid; i < 64 * 128; i += 256) {
        int r = i >> 7, c = i & 127;
        int node = base + r;
        float v = (c < INDIM && node < NN) ? x[(size_t)node * INDIM + c] : 0.f;
        xs[r * XROW + c] = f2bf(v);
    }
    __syncthreads();
    int wave = tid >> 6, lane = tid & 63;
    int quad = lane >> 4, l15 = lane & 15;
#pragma unroll
    for (int nt = 0; nt < 4; ++nt) {
        floatx4 c = {0.f, 0.f, 0.f, 0.f};
#pragma unroll
        for (int kk = 0; kk < 4; ++kk) {
            short8 a = *(const short8*)&xs[(wave * 16 + l15) * XROW + kk * 32 + quad * 8];
            short8 bb = *(const short8*)&w1T[(nt * 16 + l15) * 128 + kk * 32 + quad * 8];
            c = __builtin_amdgcn_mfma_f32_16x16x32_bf16(a, bb, c, 0, 0, 0);
        }
        int col = nt * 16 + l15;
#pragma unroll
        for (int r = 0; r < 4; ++r) {
            int row = base + wave * 16 + quad * 4 + r;
            if (row < NN) y[(size_t)row * 64 + col] = f2bf(c[r]);
        }
    }
}

// ---------------- fused layer: 4-wave/16-node blocks for full occupancy ----------------

template <bool HAS_NEXT>
__global__ __launch_bounds__(256) void k_layer(const unsigned short* __restrict__ y,
                                               const int* __restrict__ count,
                                               const int* __restrict__ csr,
                                               const float* __restrict__ b1,
                                               const unsigned short* __restrict__ w2T,  // bf16 [n][k]
                                               const float* __restrict__ b2,
                                               const unsigned short* __restrict__ wnT,  // bf16 [n][k]
                                               unsigned short* __restrict__ ynext,
                                               const int* __restrict__ batch,
                                               float* __restrict__ gp) {
    __shared__ __align__(16) unsigned short tA[16 * LROW];
    __shared__ __align__(16) unsigned short tB[16 * LROW];
    int wave = threadIdx.x >> 6, lane = threadIdx.x & 63;
    int base = blockIdx.x * 16;  // NN = 3125 * 16 exactly
    float bias1 = b1[lane];

    // ---- gather: wave handles nodes wave*4..wave*4+3, 2 interleaved per pass ----
    for (int i = 0; i < 4; i += 2) {
        int nA = __builtin_amdgcn_readfirstlane(base + wave * 4 + i);
        int nB = __builtin_amdgcn_readfirstlane(base + wave * 4 + i + 1);
        int cA = min(count[nA], CSR_CAP);
        int cB = min(count[nB], CSR_CAP);
        const int* pA = csr + (size_t)nA * CSR_CAP;
        const int* pB = csr + (size_t)nB * CSR_CAP;
        float aA[4], aB[4];
        aA[0] = bf2f(y[(size_t)nA * 64 + lane]);
        aB[0] = bf2f(y[(size_t)nB * 64 + lane]);
        aA[1] = aA[2] = aA[3] = 0.f;
        aB[1] = aB[2] = aB[3] = 0.f;
        int eA = 0, eB = 0;
        while (eA + 8 <= cA && eB + 8 <= cB) {
            int iA[8], iB[8];
#pragma unroll
            for (int j = 0; j < 8; ++j) { iA[j] = pA[eA + j]; iB[j] = pB[eB + j]; }
            float vA[8], vB[8];
#pragma unroll
            for (int j = 0; j < 8; ++j) vA[j] = bf2f(y[(size_t)iA[j] * 64 + lane]);
#pragma unroll
            for (int j = 0; j < 8; ++j) vB[j] = bf2f(y[(size_t)iB[j] * 64 + lane]);
#pragma unroll
            for (int j = 0; j < 8; ++j) { aA[j & 3] += vA[j]; aB[j & 3] += vB[j]; }
            eA += 8; eB += 8;
        }
        for (; eA + 8 <= cA; eA += 8) {
            int idx[8];
#pragma unroll
            for (int j = 0; j < 8; ++j) idx[j] = pA[eA + j];
#pragma unroll
            for (int j = 0; j < 8; ++j) aA[j & 3] += bf2f(y[(size_t)idx[j] * 64 + lane]);
        }
        if (eA + 4 <= cA) {
            int i0 = pA[eA], i1 = pA[eA + 1], i2 = pA[eA + 2], i3 = pA[eA + 3];
            aA[0] += bf2f(y[(size_t)i0 * 64 + lane]);
            aA[1] += bf2f(y[(size_t)i1 * 64 + lane]);
            aA[2] += bf2f(y[(size_t)i2 * 64 + lane]);
            aA[3] += bf2f(y[(size_t)i3 * 64 + lane]);
            eA += 4;
        }
        if (eA + 2 <= cA) {
            int i0 = pA[eA], i1 = pA[eA + 1];
            aA[0] += bf2f(y[(size_t)i0 * 64 + lane]);
            aA[1] += bf2f(y[(size_t)i1 * 64 + lane]);
            eA += 2;
        }
        if (eA < cA) aA[0] += bf2f(y[(size_t)pA[eA] * 64 + lane]);
        for (; eB + 8 <= cB; eB += 8) {
            int idx[8];
#pragma unroll
            for (int j = 0; j < 8; ++j) idx[j] = pB[eB + j];
#pragma unroll
            for (int j = 0; j < 8; ++j) aB[j & 3] += bf2f(y[(size_t)idx[j] * 64 + lane]);
        }
        if (eB + 4 <= cB) {
            int i0 = pB[eB], i1 = pB[eB + 1], i2 = pB[eB + 2], i3 = pB[eB + 3];
            aB[0] += bf2f(y[(size_t)i0 * 64 + lane]);
            aB[1] += bf2f(y[(size_t)i1 * 64 + lane]);
            aB[2] += bf2f(y[(size_t)i2 * 64 + lane]);
            aB[3] += bf2f(y[(size_t)i3 * 64 + lane]);
            eB += 4;
        }
        if (eB + 2 <= cB) {
            int i0 = pB[eB], i1 = pB[eB + 1];
            aB[0] += bf2f(y[(size_t)i0 * 64 + lane]);
            aB[1] += bf2f(y[(size_t)i1 * 64 + lane]);
            eB += 2;
        }
        if (eB < cB) aB[0] += bf2f(y[(size_t)pB[eB] * 64 + lane]);

        float sA = (aA[0] + aA[1]) + (aA[2] + aA[3]);
        float sB = (aB[0] + aB[1]) + (aB[2] + aB[3]);
        tA[(wave * 4 + i) * LROW + lane]     = f2bf(fmaxf(sA + bias1, 0.f));
        tA[(wave * 4 + i + 1) * LROW + lane] = f2bf(fmaxf(sB + bias1, 0.f));
    }
    __syncthreads();

    int quad = lane >> 4, l15 = lane & 15;

    // ---- GEMM1: h = relu(t @ w2 + b2) -> tB; 4 n-tiles, 1 per wave ----
    short8 a_k0 = *(const short8*)&tA[l15 * LROW + quad * 8];
    short8 a_k1 = *(const short8*)&tA[l15 * LROW + 32 + quad * 8];
    {
        int col = wave * 16 + l15;
        short8 b_k0 = *(const short8*)&w2T[col * 64 + quad * 8];
        short8 b_k1 = *(const short8*)&w2T[col * 64 + 32 + quad * 8];
        floatx4 c = {0.f, 0.f, 0.f, 0.f};
        c = __builtin_amdgcn_mfma_f32_16x16x32_bf16(a_k0, b_k0, c, 0, 0, 0);
        c = __builtin_amdgcn_mfma_f32_16x16x32_bf16(a_k1, b_k1, c, 0, 0, 0);
        float bb = b2[col];
#pragma unroll
        for (int r = 0; r < 4; ++r) {
            float h = fmaxf(c[r] + bb, 0.f);  // inter-layer ReLU
            tB[(quad * 4 + r) * LROW + col] = f2bf(h);
        }
    }
    __syncthreads();

    // ---- block-level segmented pool: wave 0 scans 16 rows ----
    if (wave == 0) {
        float run = 0.f;
        int curg = batch[base];
        for (int r = 0; r < 16; ++r) {
            int g2 = batch[base + r];
            if (g2 != curg) {
                atomicAdd(&gp[curg * 64 + lane], run);
                run = 0.f;
                curg = g2;
            }
            run += bf2f(tB[r * LROW + lane]);
        }
        atomicAdd(&gp[curg * 64 + lane], run);
    }

    if (HAS_NEXT) {
        // ---- GEMM3: yn = h @ wnext; 1 n-tile per wave ----
        short8 h_k0 = *(const short8*)&tB[l15 * LROW + quad * 8];
        short8 h_k1 = *(const short8*)&tB[l15 * LROW + 32 + quad * 8];
        int col = wave * 16 + l15;
        short8 w_k0 = *(const short8*)&wnT[col * 64 + quad * 8];
        short8 w_k1 = *(const short8*)&wnT[col * 64 + 32 + quad * 8];
        floatx4 cy = {0.f, 0.f, 0.f, 0.f};
        cy = __builtin_amdgcn_mfma_f32_16x16x32_bf16(h_k0, w_k0, cy, 0, 0, 0);
        cy = __builtin_amdgcn_mfma_f32_16x16x32_bf16(h_k1, w_k1, cy, 0, 0, 0);
#pragma unroll
        for (int r = 0; r < 4; ++r) {
            int row = base + quad * 4 + r;
            ynext[(size_t)row * 64 + col] = f2bf(cy[r]);
        }
    }
}

// ---------------- final head: pooled-JK + ffn + out; graph size via binary search ----------------

__device__ inline int lbound(const int* __restrict__ b, int v) {
    int lo = 0, hi = NN;
    while (lo < hi) {
        int m = (lo + hi) >> 1;
        if (b[m] < v) lo = m + 1; else hi = m;
    }
    return lo;
}

__global__ __launch_bounds__(64) void k_final(const float* __restrict__ gp,   // [3][NG][64]
                                              const int* __restrict__ batch,  // sorted
                                              const float* __restrict__ jkw,  // fp32 [192][64]
                                              const float* __restrict__ jkb,
                                              const float* __restrict__ w1,
                                              const float* __restrict__ b1,
                                              const float* __restrict__ bng,
                                              const float* __restrict__ bnb,
                                              const float* __restrict__ bnm,
                                              const float* __restrict__ bnv,
                                              const float* __restrict__ w2,
                                              const float* __restrict__ b2,
                                              const float* __restrict__ ow,
                                              const float* __restrict__ ob,
                                              float* __restrict__ out) {
    __shared__ float gs[192];
    __shared__ float gv[64];
    __shared__ float t2[64];
    __shared__ float t3[64];
    int gr = blockIdx.x, lane = threadIdx.x;
    gs[lane]       = gp[0 * NG * 64 + gr * 64 + lane];
    gs[64 + lane]  = gp[1 * NG * 64 + gr * 64 + lane];
    gs[128 + lane] = gp[2 * NG * 64 + gr * 64 + lane];
    float cntf = (float)(lbound(batch, gr + 1) - lbound(batch, gr));
    __syncthreads();
    float acc = cntf * jkb[lane];
#pragma unroll 8
    for (int k = 0; k < 192; ++k) acc = fmaf(gs[k], jkw[k * 64 + lane], acc);
    gv[lane] = acc;
    __syncthreads();
    acc = b1[lane];
#pragma unroll 8
    for (int k = 0; k < 64; ++k) acc = fmaf(gv[k], w1[k * 64 + lane], acc);
    acc = (acc - bnm[lane]) * rsqrtf(bnv[lane] + 1e-5f) * bng[lane] + bnb[lane];
    t2[lane] = fmaxf(acc, 0.f);
    __syncthreads();
    float acc2 = b2[lane];
#pragma unroll 8
    for (int k = 0; k < 64; ++k) acc2 = fmaf(t2[k], w2[k * 64 + lane], acc2);
    t3[lane] = acc2;
    __syncthreads();
    if (lane < OUTD) {
        float acc3 = ob[lane];
#pragma unroll 8
        for (int k = 0; k < 64; ++k) acc3 = fmaf(t3[k], ow[k * OUTD + lane], acc3);
        out[gr * OUTD + lane] = acc3;
    }
}

extern "C" void kernel_launch(void* const* d_in, const int* in_sizes, int n_in,
                              void* d_out, int out_size, void* d_ws, size_t ws_size,
                              hipStream_t stream) {
    const float* x     = (const float*)d_in[0];
    const int*   ei    = (const int*)d_in[1];
    const int*   batch = (const int*)d_in[2];
    const float* w1_0 = (const float*)d_in[3];
    const float* b1_0 = (const float*)d_in[4];
    const float* w2_0 = (const float*)d_in[5];
    const float* b2_0 = (const float*)d_in[6];
    const float* w1_1 = (const float*)d_in[7];
    const float* b1_1 = (const float*)d_in[8];
    const float* w2_1 = (const float*)d_in[9];
    const float* b2_1 = (const float*)d_in[10];
    const float* w1_2 = (const float*)d_in[11];
    const float* b1_2 = (const float*)d_in[12];
    const float* w2_2 = (const float*)d_in[13];
    const float* b2_2 = (const float*)d_in[14];
    const float* jk_w = (const float*)d_in[15];
    const float* jk_b = (const float*)d_in[16];
    const float* ffn_w1 = (const float*)d_in[17];
    const float* ffn_b1 = (const float*)d_in[18];
    const float* bn_g = (const float*)d_in[19];
    const float* bn_b = (const float*)d_in[20];
    const float* bn_m = (const float*)d_in[21];
    const float* bn_v = (const float*)d_in[22];
    const float* ffn_w2 = (const float*)d_in[23];
    const float* ffn_b2 = (const float*)d_in[24];
    const float* out_w  = (const float*)d_in[25];
    const float* out_b  = (const float*)d_in[26];

    // workspace layout
    float* ws = (float*)d_ws;
    unsigned short* ya = (unsigned short*)ws;          // 3.2M bf16
    unsigned short* yb = ya + 3200000;                 // 3.2M bf16
    float* gp  = (float*)(yb + 3200000);               // 3 x NG x 64 fp32
    int*   count = (int*)(gp + 3 * NG * 64);           // 50000
    int*   csr   = count + NN;                         // NN * CSR_CAP ints = 12.8MB
    unsigned short* wT  = (unsigned short*)(csr + (size_t)NN * CSR_CAP);  // 5 x 4096 bf16
    unsigned short* w0T = wT + 5 * 4096;                                  // 64 x 128 bf16

    // ---- prep: weight transposes + zero count/gp (one dispatch) ----
    k_prep<<<B_GP0, 256, 0, stream>>>(w2_0, w2_1, w2_2, w1_1, w1_2, w1_0,
                                      wT, w0T, count, gp);

    // ---- CSR fill | y0 MFMA ----
    k_fill<<<NPART * 192, 256, 0, stream>>>(ei, count, csr);
    k_pre0<<<(NN + 63) / 64, 256, 0, stream>>>(x, w0T, ya);

    int nblk = NN / 16;  // 3125, exact
    // ---- layer 0 ----
    k_layer<true><<<nblk, 256, 0, stream>>>(ya, count, csr, b1_0,
                                            wT + 0 * 4096, b2_0, wT + 3 * 4096,
                                            yb, batch, gp + 0 * NG * 64);
    // ---- layer 1 ----
    k_layer<true><<<nblk, 256, 0, stream>>>(yb, count, csr, b1_1,
                                            wT + 1 * 4096, b2_1, wT + 4 * 4096,
                                            ya, batch, gp + 1 * NG * 64);
    // ---- layer 2 ----
    k_layer<false><<<nblk, 256, 0, stream>>>(ya, count, csr, b1_2,
                                             wT + 2 * 4096, b2_2, nullptr,
                                             nullptr, batch, gp + 2 * NG * 64);

    // ---- head (pooled-JK + ffn + out; graph sizes via binary search) ----
    k_final<<<NG, 64, 0, stream>>>(gp, batch, jk_w, jk_b,
                                   ffn_w1, ffn_b1, bn_g, bn_b, bn_m, bn_v,
                                   ffn_w2, ffn_b2, out_w, out_b, (float*)d_out);
}